// Round 2
// baseline (2058.679 us; speedup 1.0000x reference)
//
#include <hip/hip_runtime.h>
#include <stdint.h>
#include <stddef.h>

// Problem: y[m][n] = (sum_k x[m][k] * w[k][n]) * scale[n] + bias[n]
// M = 8192 (B*S), K = 4096 (DIN), N = 16384 (NF)
// x fp32; w int8 in reference but harness widens integer inputs to int32;
// scale/bias fp32; out fp32.

#define M_DIM 8192
#define K_DIM 4096
#define N_DIM 16384

typedef unsigned short u16;
typedef __attribute__((ext_vector_type(8))) short   short8;   // 8 x bf16 (MFMA A/B frag)
typedef __attribute__((ext_vector_type(8))) u16     ushort8;
typedef __attribute__((ext_vector_type(4))) float   floatx4;  // MFMA C/D frag
typedef __attribute__((ext_vector_type(4))) int     intx4;

// float -> bf16, round-to-nearest-even (inputs are finite normals)
__device__ __forceinline__ u16 f2bf_rne(float f) {
    unsigned u = __float_as_uint(f);
    return (u16)((u + 0x7fffu + ((u >> 16) & 1u)) >> 16);
}

// ---------------------------------------------------------------------------
// Kernel 1: x fp32 [8192][4096] -> bf16 same layout.
// 33,554,432 elements = 16384 blocks * 256 threads * 8 elems (exact fit).
// ---------------------------------------------------------------------------
__global__ __launch_bounds__(256) void cvt_x_bf16(const float* __restrict__ x,
                                                  u16* __restrict__ xb) {
    size_t e = ((size_t)blockIdx.x * 256 + threadIdx.x) * 8;
    floatx4 a = *(const floatx4*)(x + e);
    floatx4 b = *(const floatx4*)(x + e + 4);
    ushort8 o;
    o[0] = f2bf_rne(a[0]); o[1] = f2bf_rne(a[1]);
    o[2] = f2bf_rne(a[2]); o[3] = f2bf_rne(a[3]);
    o[4] = f2bf_rne(b[0]); o[5] = f2bf_rne(b[1]);
    o[6] = f2bf_rne(b[2]); o[7] = f2bf_rne(b[3]);
    *(ushort8*)(xb + e) = o;
}

// ---------------------------------------------------------------------------
// Kernel 2: weight int32 [K=4096][N=16384] (values in [-128,127]) -> bf16
// transposed Wt [N][K]. int8-range ints are exact in bf16 (<=8 significand
// bits), so f32 bit-truncation after v_cvt_f32_i32 is exact.
// Block: 256 threads = 256 n (one per thread) x 256 k per block.
// Loads: per (kk,j) a wave reads 256 consecutive bytes -> fully coalesced.
// Stores: each lane writes 16 B x 32 = 512 B contiguous along K.
// Grid: (N/256, K/256) = (64, 16).
// ---------------------------------------------------------------------------
__global__ __launch_bounds__(256) void cvt_w_t(const int* __restrict__ w,
                                               u16* __restrict__ wt) {
    const int n = blockIdx.x * 256 + threadIdx.x;
    const size_t k0 = (size_t)blockIdx.y * 256;
    u16* dst = wt + (size_t)n * K_DIM + k0;
    for (int kk = 0; kk < 32; ++kk) {
        const size_t k = k0 + (size_t)kk * 8;
        ushort8 o;
#pragma unroll
        for (int j = 0; j < 8; ++j) {
            float f = (float)w[(k + j) * (size_t)N_DIM + n];
            o[j] = (u16)(__float_as_uint(f) >> 16);   // exact for |v| <= 128
        }
        *(ushort8*)(dst + kk * 8) = o;
    }
}

// ---------------------------------------------------------------------------
// Kernel 3: bf16 GEMM, m97 structure.
//   C[m][n] = sum_k A[m][k] * Wt[n][k]   (both operands row-major with K inner)
//   128x128 tile, BK=32, 256 threads = 4 waves in 2x2, each wave 64x64 output
//   as 4x4 grid of 16x16x32 MFMAs. global_load_lds width=16 staging.
// Epilogue: out = acc * scale[n] + bias[n], fp32.
// ---------------------------------------------------------------------------
__device__ __forceinline__ void async_copy16(u16* lds, const u16* g) {
    __builtin_amdgcn_global_load_lds(
        (const __attribute__((address_space(1))) void*)g,
        (__attribute__((address_space(3))) void*)lds,
        16, 0, 0);
}

__global__ __launch_bounds__(256) void gemm_bf16(const u16* __restrict__ A,
                                                 const u16* __restrict__ B,
                                                 const float* __restrict__ scale,
                                                 const float* __restrict__ bias,
                                                 float* __restrict__ C) {
    // LDS: no padding (global_load_lds needs lane-contiguous layout).
    // Fragment ds_read_b128: row stride 64 B = 16 banks -> 2-way alias = free (m136).
    __shared__ u16 As[128 * 32];
    __shared__ u16 Bs[128 * 32];

    const int t  = threadIdx.x;
    const int w  = t >> 6;       // wave 0..3
    const int l  = t & 63;       // lane
    const int q  = l >> 4;       // quad 0..3
    const int r  = l & 15;
    const int m0 = blockIdx.y * 128;
    const int n0 = blockIdx.x * 128;
    const int wm = (w & 1) * 64; // wave's m offset in tile
    const int wn = (w >> 1) * 64;

    floatx4 acc[4][4] = {};      // 64 VGPRs of accumulator

    // Staging: thread t covers row (t>>2), cols (t&3)*8 .. +7 of the 128x32
    // tile half; LDS dest byte = t*16 (wave-uniform base + lane*16 -- legal).
    const u16* ag = A + (size_t)(m0 + (t >> 2)) * K_DIM + (t & 3) * 8;
    const u16* bg = B + (size_t)(n0 + (t >> 2)) * K_DIM + (t & 3) * 8;
    u16* as0 = &As[t * 8];
    u16* as1 = &As[2048 + t * 8];
    u16* bs0 = &Bs[t * 8];
    u16* bs1 = &Bs[2048 + t * 8];
    const size_t rowskip = (size_t)64 * K_DIM;

    for (int k0 = 0; k0 < K_DIM; k0 += 32) {
        async_copy16(as0, ag);
        async_copy16(as1, ag + rowskip);
        async_copy16(bs0, bg);
        async_copy16(bs1, bg + rowskip);
        ag += 32;
        bg += 32;
        __syncthreads();   // compiler drains vmcnt before s_barrier

        short8 af[4], bf[4];
#pragma unroll
        for (int i = 0; i < 4; ++i) {
            // A-frag: lane holds A[m = r][k = q*8 + j]
            af[i] = *(const short8*)&As[(wm + i * 16 + r) * 32 + q * 8];
            // B-frag: lane holds B[k = q*8 + j][n = r]  (Wt is [n][k])
            bf[i] = *(const short8*)&Bs[(wn + i * 16 + r) * 32 + q * 8];
        }
#pragma unroll
        for (int i = 0; i < 4; ++i)
#pragma unroll
            for (int j = 0; j < 4; ++j)
                acc[i][j] = __builtin_amdgcn_mfma_f32_16x16x32_bf16(
                    af[i], bf[j], acc[i][j], 0, 0, 0);

        __syncthreads();   // fragment reads done before next stage overwrites
    }

    // Epilogue. C/D layout (m89/m91 verified): col(n) = lane&15, row(m) = quad*4 + reg.
#pragma unroll
    for (int j = 0; j < 4; ++j) {
        const int cn = n0 + wn + j * 16 + r;
        const float s  = scale[cn];
        const float bi = bias[cn];
#pragma unroll
        for (int i = 0; i < 4; ++i) {
            const int cm = m0 + wm + i * 16 + q * 4;
#pragma unroll
            for (int v = 0; v < 4; ++v) {
                C[(size_t)(cm + v) * N_DIM + cn] = acc[i][j][v] * s + bi;
            }
        }
    }
}

// ---------------------------------------------------------------------------
// Launch: ws layout = [ xb: 8192*4096*2 = 64 MiB | wt: 16384*4096*2 = 128 MiB ]
// Total ws needed: 201,326,592 bytes. Everything rewritten every call.
// ---------------------------------------------------------------------------
extern "C" void kernel_launch(void* const* d_in, const int* in_sizes, int n_in,
                              void* d_out, int out_size, void* d_ws, size_t ws_size,
                              hipStream_t stream) {
    const float* x     = (const float*)d_in[0];
    const int*   wq    = (const int*)d_in[1];    // int8 weight widened to int32, [K][N]
    const float* scale = (const float*)d_in[2];  // [N]
    const float* bias  = (const float*)d_in[3];  // [N]
    float*       out   = (float*)d_out;          // [M][N]

    u16* xb = (u16*)d_ws;                                      // bf16 x [M][K]
    u16* wt = (u16*)((char*)d_ws + (size_t)M_DIM * K_DIM * 2); // bf16 Wt [N][K]

    cvt_x_bf16<<<dim3((M_DIM * K_DIM) / (256 * 8)), dim3(256), 0, stream>>>(x, xb);
    cvt_w_t<<<dim3(N_DIM / 256, K_DIM / 256), dim3(256), 0, stream>>>(wq, wt);
    gemm_bf16<<<dim3(N_DIM / 128, M_DIM / 128), dim3(256), 0, stream>>>(xb, wt, scale, bias, out);
}